// Round 1
// baseline (16524.924 us; speedup 1.0000x reference)
//
#include <hip/hip_runtime.h>

#define S_ 512
#define B_ 64
#define I_ 512
#define H_ 1024
#define O_ 512
#define C_ 1536   // I_ + H_
#define NG_ 4096  // 4*H_

typedef unsigned short u16;
typedef __attribute__((ext_vector_type(8))) short bf16x8;
typedef __attribute__((ext_vector_type(8))) unsigned short u16x8;
typedef __attribute__((ext_vector_type(4))) float f32x4;

__device__ __forceinline__ u16 f2bf(float f) {
    union { float f; unsigned int u; } v; v.f = f;
    unsigned int u = v.u;
    unsigned int r = (u + 0x7fffu + ((u >> 16) & 1u)) >> 16;
    return (u16)r;
}
__device__ __forceinline__ float bf2f(u16 h) {
    union { unsigned int u; float f; } v; v.u = ((unsigned int)h) << 16;
    return v.f;
}
__device__ __forceinline__ float sigm(float x) { return 1.0f / (1.0f + __expf(-x)); }

// ---- packing kernels -------------------------------------------------------

__global__ void k_pack_w(const float* __restrict__ Wf, const float* __restrict__ Wi,
                         const float* __restrict__ Wo, const float* __restrict__ Wg,
                         u16* __restrict__ Wall) {
    size_t i8 = ((size_t)blockIdx.x * blockDim.x + threadIdx.x) * 8;
    if (i8 >= (size_t)NG_ * C_) return;
    size_t n = i8 / C_;         // row of Wall (gate-major), C_ % 8 == 0 so one row
    size_t k = i8 - n * C_;
    const float* Ws[4] = {Wf, Wi, Wo, Wg};
    const float* src = Ws[n >> 10] + (n & 1023) * C_ + k;
    u16x8 o;
#pragma unroll
    for (int j = 0; j < 8; j++) o[j] = f2bf(src[j]);
    *(u16x8*)(Wall + i8) = o;
}

__global__ void k_pack_wy(const float* __restrict__ Wy,
                          u16* __restrict__ hi, u16* __restrict__ lo) {
    size_t i8 = ((size_t)blockIdx.x * blockDim.x + threadIdx.x) * 8;
    if (i8 >= (size_t)O_ * H_) return;
    u16x8 oh, ol;
#pragma unroll
    for (int j = 0; j < 8; j++) {
        float v = Wy[i8 + j];
        oh[j] = f2bf(v);
        ol[j] = f2bf(v - bf2f(oh[j]));
    }
    *(u16x8*)(hi + i8) = oh;
    *(u16x8*)(lo + i8) = ol;
}

__global__ void k_pack_x(const float* __restrict__ x, u16* __restrict__ xb) {
    size_t i8 = ((size_t)blockIdx.x * blockDim.x + threadIdx.x) * 8;
    if (i8 >= (size_t)S_ * B_ * I_) return;
    u16x8 o;
#pragma unroll
    for (int j = 0; j < 8; j++) o[j] = f2bf(x[i8 + j]);
    *(u16x8*)(xb + i8) = o;
}

// ---- one LSTM time step ----------------------------------------------------
// grid: 64 blocks (hidden slice of 16), 256 threads (wave w == gate w)
__global__ __launch_bounds__(256) void k_step(
    const u16* __restrict__ Wall,   // [4096][1536] bf16
    const u16* __restrict__ xbf,    // [S][64][512] bf16
    const float* __restrict__ bfv, const float* __restrict__ biv,
    const float* __restrict__ bov, const float* __restrict__ bgv,
    u16* __restrict__ hhi,          // [S+1][64][1024] bf16 (slot t = h_t)
    u16* __restrict__ hlo,          // [S+1][64][1024] bf16 residual
    float* __restrict__ cst,        // [64][1024] fp32 cell state
    int t)
{
    const int tid = threadIdx.x;
    const int wv = tid >> 6;        // gate index 0..3 (f,i,o,g)
    const int lane = tid & 63;
    const int la = lane & 15;       // A-row / B-col / C-col within tile
    const int kg = (lane >> 4) * 8; // k offset within K=32 chunk
    const int j0 = blockIdx.x * 16;

    const u16* xt = xbf + (size_t)t * (B_ * I_);
    const u16* hp = hhi + (size_t)t * (B_ * H_);
    const u16* bp = Wall + (size_t)(wv * H_ + j0 + la) * C_ + kg;

    f32x4 acc[4];
#pragma unroll
    for (int m = 0; m < 4; m++) acc[m] = (f32x4){0.f, 0.f, 0.f, 0.f};

    // x part of the combined GEMM: K = 512
    for (int k = 0; k < I_; k += 32) {
        bf16x8 bb = *(const bf16x8*)(bp + k);
#pragma unroll
        for (int m = 0; m < 4; m++) {
            bf16x8 aa = *(const bf16x8*)(xt + (size_t)(m * 16 + la) * I_ + k + kg);
            acc[m] = __builtin_amdgcn_mfma_f32_16x16x32_bf16(aa, bb, acc[m], 0, 0, 0);
        }
    }
    // h part: K = 1024
    const u16* bp2 = bp + I_;
    for (int k = 0; k < H_; k += 32) {
        bf16x8 bb = *(const bf16x8*)(bp2 + k);
#pragma unroll
        for (int m = 0; m < 4; m++) {
            bf16x8 aa = *(const bf16x8*)(hp + (size_t)(m * 16 + la) * H_ + k + kg);
            acc[m] = __builtin_amdgcn_mfma_f32_16x16x32_bf16(aa, bb, acc[m], 0, 0, 0);
        }
    }

    // exchange the 4 gate tiles through LDS
    __shared__ float gl[4][64][16];
#pragma unroll
    for (int m = 0; m < 4; m++) {
#pragma unroll
        for (int r = 0; r < 4; r++) {
            int row = m * 16 + (lane >> 4) * 4 + r;  // batch row
            gl[wv][row][la] = acc[m][r];
        }
    }
    __syncthreads();

    u16* ho = hhi + (size_t)(t + 1) * (B_ * H_);
    u16* lo = hlo + (size_t)(t + 1) * (B_ * H_);
    for (int e = tid; e < 1024; e += 256) {
        int b = e >> 4, jj = e & 15;
        int j = j0 + jj;
        float f = sigm(gl[0][b][jj] + bfv[j]);
        float i = sigm(gl[1][b][jj] + biv[j]);
        float o = sigm(gl[2][b][jj] + bov[j]);
        float g = tanhf(gl[3][b][jj] + bgv[j]);
        float cn = f * cst[b * H_ + j] + i * g;
        float hn = o * tanhf(cn);
        cst[b * H_ + j] = cn;
        u16 hb = f2bf(hn);
        ho[b * H_ + j] = hb;
        lo[b * H_ + j] = f2bf(hn - bf2f(hb));
    }
}

// ---- final projection: out = H_all @ Wy^T + by (hi/lo split, ~fp32 quality)
// grid: (512, 8) blocks of 256; block tile 64x64
__global__ __launch_bounds__(256) void k_pred(
    const u16* __restrict__ ah,     // [32768][1024] bf16 (h hi, slots 1..512)
    const u16* __restrict__ al,     // matching residuals
    const u16* __restrict__ wyh,    // [512][1024] bf16
    const u16* __restrict__ wyl,
    const float* __restrict__ by,
    float* __restrict__ out)        // [32768][512] fp32
{
    const int tid = threadIdx.x;
    const int wv = tid >> 6;
    const int lane = tid & 63;
    const int la = lane & 15;
    const int kg = (lane >> 4) * 8;
    const int m0 = blockIdx.x * 64;
    const int n0 = blockIdx.y * 64 + wv * 16;

    const u16* bh = wyh + (size_t)(n0 + la) * H_ + kg;
    const u16* bl = wyl + (size_t)(n0 + la) * H_ + kg;

    f32x4 acc[4];
#pragma unroll
    for (int m = 0; m < 4; m++) acc[m] = (f32x4){0.f, 0.f, 0.f, 0.f};

    for (int k = 0; k < H_; k += 32) {
        bf16x8 bhh = *(const bf16x8*)(bh + k);
        bf16x8 bll = *(const bf16x8*)(bl + k);
#pragma unroll
        for (int m = 0; m < 4; m++) {
            size_t arow = (size_t)(m0 + m * 16 + la);
            bf16x8 aa = *(const bf16x8*)(ah + arow * H_ + k + kg);
            bf16x8 aal = *(const bf16x8*)(al + arow * H_ + k + kg);
            acc[m] = __builtin_amdgcn_mfma_f32_16x16x32_bf16(aal, bhh, acc[m], 0, 0, 0);
            acc[m] = __builtin_amdgcn_mfma_f32_16x16x32_bf16(aa, bll, acc[m], 0, 0, 0);
            acc[m] = __builtin_amdgcn_mfma_f32_16x16x32_bf16(aa, bhh, acc[m], 0, 0, 0);
        }
    }

#pragma unroll
    for (int m = 0; m < 4; m++) {
#pragma unroll
        for (int r = 0; r < 4; r++) {
            int row = m0 + m * 16 + (lane >> 4) * 4 + r;
            int col = n0 + la;
            out[(size_t)row * O_ + col] = acc[m][r] + by[col];
        }
    }
}

// ---- host ------------------------------------------------------------------

extern "C" void kernel_launch(void* const* d_in, const int* in_sizes, int n_in,
                              void* d_out, int out_size, void* d_ws, size_t ws_size,
                              hipStream_t stream) {
    const float* x   = (const float*)d_in[0];
    const float* Wf  = (const float*)d_in[1];
    const float* bfv = (const float*)d_in[2];
    const float* Wi  = (const float*)d_in[3];
    const float* biv = (const float*)d_in[4];
    const float* Wo  = (const float*)d_in[5];
    const float* bov = (const float*)d_in[6];
    const float* Wg  = (const float*)d_in[7];
    const float* bgv = (const float*)d_in[8];
    const float* Wy  = (const float*)d_in[9];
    const float* by  = (const float*)d_in[10];
    float* out = (float*)d_out;

    char* ws = (char*)d_ws;
    size_t off = 0;
    auto alloc = [&](size_t bytes) {
        char* p = ws + off;
        off += (bytes + 255) & ~(size_t)255;
        return p;
    };
    u16*   Wall = (u16*)alloc((size_t)NG_ * C_ * 2);        // 12.6 MB
    u16*   Wyhi = (u16*)alloc((size_t)O_ * H_ * 2);         // 1 MB
    u16*   Wylo = (u16*)alloc((size_t)O_ * H_ * 2);         // 1 MB
    u16*   xbf  = (u16*)alloc((size_t)S_ * B_ * I_ * 2);    // 33.6 MB
    float* cst  = (float*)alloc((size_t)B_ * H_ * 4);       // 0.26 MB
    u16*   hhi  = (u16*)alloc((size_t)(S_ + 1) * B_ * H_ * 2);  // 67.2 MB
    u16*   hlo  = (u16*)alloc((size_t)(S_ + 1) * B_ * H_ * 2);  // 67.2 MB

    // zero cell state and h_0 (slot 0)
    (void)hipMemsetAsync(cst, 0, (size_t)B_ * H_ * 4, stream);
    (void)hipMemsetAsync(hhi, 0, (size_t)B_ * H_ * 2, stream);

    k_pack_w <<<3072, 256, 0, stream>>>(Wf, Wi, Wo, Wg, Wall);
    k_pack_wy<<<256,  256, 0, stream>>>(Wy, Wyhi, Wylo);
    k_pack_x <<<8192, 256, 0, stream>>>(x, xbf);

    for (int t = 0; t < S_; t++)
        k_step<<<64, 256, 0, stream>>>(Wall, xbf, bfv, biv, bov, bgv, hhi, hlo, cst, t);

    k_pred<<<dim3(512, 8), 256, 0, stream>>>(hhi + (size_t)B_ * H_, hlo + (size_t)B_ * H_,
                                             Wyhi, Wylo, by, out);
}